// Round 2
// baseline (968.787 us; speedup 1.0000x reference)
//
#include <hip/hip_runtime.h>

// MoE grouped GEMM: Y[T, OUT] = X[T, IN] @ W[e, OUT, IN]^T + bias[e, OUT]
// tokens sorted by expert; expert_offset[E+1] gives segment boundaries.
//
// Round 2: identical structure to round 1 (128x128 tile, BK=32, bf16 MFMA
// 16x16x32, fp32->bf16 cvt during LDS staging), but expert_offset is read as
// int32 (harness converts integer inputs to int32). A device-side
// discriminator handles the int64 case defensively: p32[NEXP] == T iff int32
// layout (under int64 layout that word is the low half of off[4] < T).

typedef __attribute__((ext_vector_type(8))) short s16x8;   // 8 bf16 (4 VGPRs)
typedef __attribute__((ext_vector_type(4))) short s16x4;   // 4 bf16 (8 B)
typedef __attribute__((ext_vector_type(4))) float f32x4;

#define BM 128
#define BN 128
#define BK 32
#define LDK 40   // LDS leading dim in bf16 elems: 80 B row stride (16B-aligned, 20-bank)

__device__ __forceinline__ short f2bf(float f) {
    // round-to-nearest-even fp32 -> bf16 (inputs are finite; no NaN handling)
    union { float f; unsigned u; } v; v.f = f;
    unsigned r = v.u + 0x7FFFu + ((v.u >> 16) & 1u);
    return (short)(r >> 16);
}

__device__ __forceinline__ long long load_off(const void* p, int i, bool i64) {
    if (i64) return ((const long long*)p)[i];
    return (long long)((const int*)p)[i];
}

__global__ __launch_bounds__(256, 2)
void moe_gemm_kernel(const float* __restrict__ X,
                     const void* __restrict__ offp,
                     const float* __restrict__ W,
                     const float* __restrict__ Bias,
                     float* __restrict__ Y,
                     int IN_F, int OUT_F, int NEXP, int Ttot) {
    // offset dtype discriminator (wave-uniform scalar load)
    const bool off_i64 = (((const int*)offp)[NEXP] != Ttot);

    // ---- tile scheduling: map (blockIdx.y) -> (expert, local row tile) ----
    const int slot = blockIdx.y;
    int e_found = -1;
    long long row0 = 0;
    int rows = 0;
    {
        int acc_t = 0;
        for (int e = 0; e < NEXP; ++e) {
            long long s = load_off(offp, e, off_i64);
            long long t = load_off(offp, e + 1, off_i64);
            int n = (int)(t - s);
            int nt = (n + BM - 1) / BM;
            if (slot < acc_t + nt) {
                int lt = slot - acc_t;
                row0 = s + (long long)lt * BM;
                rows = (int)(t - row0);
                if (rows > BM) rows = BM;
                e_found = e;
                break;
            }
            acc_t += nt;
        }
    }
    if (e_found < 0) return;

    const int n0 = blockIdx.x * BN;
    const int tid = threadIdx.x;
    const int wave = tid >> 6;
    const int lane = tid & 63;
    const int wm = (wave & 1) * 64;    // wave's row offset within block tile
    const int wn = (wave >> 1) * 64;   // wave's col offset within block tile
    const int lrow = lane & 15;
    const int kg = lane >> 4;          // 0..3

    __shared__ __align__(16) short As[BM][LDK];
    __shared__ __align__(16) short Bs[BN][LDK];

    const float* Xb = X + (size_t)row0 * IN_F;
    const float* Wb = W + (size_t)e_found * OUT_F * IN_F + (size_t)n0 * IN_F;

    f32x4 acc[4][4] = {};

    for (int k0 = 0; k0 < IN_F; k0 += BK) {
        __syncthreads();
        // ---- stage A (X tile, with row guard + zero pad) ----
        #pragma unroll
        for (int p = 0; p < 4; ++p) {
            int idx = p * 256 + tid;
            int r = idx >> 3;            // 0..127
            int kc = (idx & 7) << 2;     // 0,4,...,28
            float4 v = make_float4(0.f, 0.f, 0.f, 0.f);
            if (r < rows) v = *(const float4*)(Xb + (size_t)r * IN_F + k0 + kc);
            s16x4 b;
            b.x = f2bf(v.x); b.y = f2bf(v.y); b.z = f2bf(v.z); b.w = f2bf(v.w);
            *(s16x4*)&As[r][kc] = b;
        }
        // ---- stage B (W tile, always full: OUT_F % BN == 0) ----
        #pragma unroll
        for (int p = 0; p < 4; ++p) {
            int idx = p * 256 + tid;
            int r = idx >> 3;
            int kc = (idx & 7) << 2;
            float4 v = *(const float4*)(Wb + (size_t)r * IN_F + k0 + kc);
            s16x4 b;
            b.x = f2bf(v.x); b.y = f2bf(v.y); b.z = f2bf(v.z); b.w = f2bf(v.w);
            *(s16x4*)&Bs[r][kc] = b;
        }
        __syncthreads();

        // ---- fragments + MFMA ----
        s16x8 af[4], bf[4];
        #pragma unroll
        for (int i = 0; i < 4; ++i)
            af[i] = *(const s16x8*)&As[wm + i * 16 + lrow][kg * 8];
        #pragma unroll
        for (int j = 0; j < 4; ++j)
            bf[j] = *(const s16x8*)&Bs[wn + j * 16 + lrow][kg * 8];

        #pragma unroll
        for (int i = 0; i < 4; ++i)
            #pragma unroll
            for (int j = 0; j < 4; ++j)
                acc[i][j] = __builtin_amdgcn_mfma_f32_16x16x32_bf16(
                    af[i], bf[j], acc[i][j], 0, 0, 0);
    }

    // ---- epilogue: C/D mapping for 16x16x32: col = lane&15, row = (lane>>4)*4 + reg ----
    float bv[4];
    #pragma unroll
    for (int j = 0; j < 4; ++j)
        bv[j] = Bias[(size_t)e_found * OUT_F + n0 + wn + j * 16 + lrow];

    #pragma unroll
    for (int i = 0; i < 4; ++i) {
        #pragma unroll
        for (int r = 0; r < 4; ++r) {
            int rr = wm + i * 16 + kg * 4 + r;
            if (rr < rows) {
                float* yrow = Y + (size_t)(row0 + rr) * OUT_F + n0;
                #pragma unroll
                for (int j = 0; j < 4; ++j)
                    yrow[wn + j * 16 + lrow] = acc[i][j][r] + bv[j];
            }
        }
    }
}

extern "C" void kernel_launch(void* const* d_in, const int* in_sizes, int n_in,
                              void* d_out, int out_size, void* d_ws, size_t ws_size,
                              hipStream_t stream) {
    const float* X = (const float*)d_in[0];
    const void* off = d_in[1];               // int32 (harness) or int64 (reference) — kernel discriminates
    const float* W = (const float*)d_in[2];
    const float* Bias = (const float*)d_in[3];
    float* Y = (float*)d_out;

    const int NEXP1 = in_sizes[1];        // E + 1
    const int NEXP = NEXP1 - 1;
    const int OUT_F = in_sizes[3] / NEXP; // bias is [E, OUT]
    const int IN_F = (int)((long long)in_sizes[2] / NEXP / OUT_F); // W is [E, OUT, IN]
    const int T = in_sizes[0] / IN_F;

    const int maxRowTiles = T / BM + NEXP;   // >= sum_e ceil(n_e / BM)
    dim3 grid(OUT_F / BN, maxRowTiles);
    moe_gemm_kernel<<<grid, 256, 0, stream>>>(X, off, W, Bias, Y, IN_F, OUT_F, NEXP, T);
}

// Round 3
// 505.166 us; speedup vs baseline: 1.9178x; 1.9178x over previous
//
#include <hip/hip_runtime.h>

// MoE grouped GEMM: Y[T, OUT] = X[T, IN] @ W[e, OUT, IN]^T + bias[e, OUT]
//
// Round 3: pre-convert X and W to bf16 in d_ws (two elementwise kernels),
// then m97-structure GEMM: 128x128 tile, BK=32, global_load_lds width=16
// staging into unpadded row-major LDS (wave-uniform base + lane*16 layout),
// 16x16x32 bf16 MFMA, 4 waves x (4x4 16x16 tiles) = 64x64 per wave.
// Partial expert tiles: pre-zero A rows >= rows; exec-masked loads skip them.
// Fallback to round-2 in-kernel-cvt path if ws_size too small.

typedef __attribute__((ext_vector_type(8))) short s16x8;   // 8 bf16
typedef __attribute__((ext_vector_type(4))) short s16x4;   // 4 bf16
typedef __attribute__((ext_vector_type(4))) float f32x4;

typedef __attribute__((address_space(1))) void gv_t;       // global
typedef __attribute__((address_space(3))) void lv_t;       // LDS

#define BM 128
#define BN 128
#define BK 32

__device__ __forceinline__ short f2bf(float f) {
    union { float f; unsigned u; } v; v.f = f;
    unsigned r = v.u + 0x7FFFu + ((v.u >> 16) & 1u);
    return (short)(r >> 16);
}

__device__ __forceinline__ long long load_off(const void* p, int i, bool i64) {
    if (i64) return ((const long long*)p)[i];
    return (long long)((const int*)p)[i];
}

// ---- fp32 -> bf16 elementwise convert (float4 in, short4 out) ----
__global__ __launch_bounds__(256)
void cvt_kernel(const float* __restrict__ src, short* __restrict__ dst, int n4) {
    int i = blockIdx.x * 256 + threadIdx.x;
    if (i >= n4) return;
    float4 v = ((const float4*)src)[i];
    s16x4 b;
    b.x = f2bf(v.x); b.y = f2bf(v.y); b.z = f2bf(v.z); b.w = f2bf(v.w);
    ((s16x4*)dst)[i] = b;
}

// ---- map blockIdx.y slot -> (expert, row0, rows) ----
__device__ __forceinline__ bool sched_tile(const void* offp, bool off_i64, int NEXP,
                                           int slot, int& e_out, long long& row0, int& rows) {
    int acc_t = 0;
    for (int e = 0; e < NEXP; ++e) {
        long long s = load_off(offp, e, off_i64);
        long long t = load_off(offp, e + 1, off_i64);
        int n = (int)(t - s);
        int nt = (n + BM - 1) / BM;
        if (slot < acc_t + nt) {
            int lt = slot - acc_t;
            row0 = s + (long long)lt * BM;
            rows = (int)(t - row0);
            if (rows > BM) rows = BM;
            e_out = e;
            return true;
        }
        acc_t += nt;
    }
    return false;
}

// ---- main GEMM: bf16 inputs, global_load_lds staging (m97 structure) ----
__global__ __launch_bounds__(256)
void moe_gemm_bf16(const short* __restrict__ Xb16,
                   const void* __restrict__ offp,
                   const short* __restrict__ Wb16,
                   const float* __restrict__ Bias,
                   float* __restrict__ Y,
                   int IN_F, int OUT_F, int NEXP, int Ttot) {
    const bool off_i64 = (((const int*)offp)[NEXP] != Ttot);

    int e_found; long long row0; int rows;
    if (!sched_tile(offp, off_i64, NEXP, blockIdx.y, e_found, row0, rows)) return;

    const int n0 = blockIdx.x * BN;
    const int tid = threadIdx.x;
    const int wave = tid >> 6;
    const int lane = tid & 63;
    const int wm = (wave & 1) * 64;
    const int wn = (wave >> 1) * 64;
    const int lrow = lane & 15;
    const int kg = lane >> 4;

    // unpadded row-major: row r, elem c at [r*BK + c] (64 B rows)
    __shared__ __align__(16) short As[BM * BK];
    __shared__ __align__(16) short Bs[BN * BK];

    const short* Xb = Xb16 + (size_t)row0 * IN_F;
    const short* Wb = Wb16 + (size_t)e_found * OUT_F * IN_F + (size_t)n0 * IN_F;

    // pre-zero A rows >= rows (each 32-elem row = 4 s16x8 chunks)
    for (int c = rows * 4 + tid; c < BM * 4; c += 256)
        ((s16x8*)As)[c] = (s16x8)0;

    const int trow = tid >> 2;          // 0..63
    const int tcol = (tid & 3) * 8;     // elem offset within row (16 B chunks)

    f32x4 acc[4][4] = {};

    for (int k0 = 0; k0 < IN_F; k0 += BK) {
        __syncthreads();   // LDS reuse + (iter 0) pre-zero visibility
        #pragma unroll
        for (int q = 0; q < 2; ++q) {
            int r = q * 64 + trow;
            if (r < rows)
                __builtin_amdgcn_global_load_lds(
                    (gv_t*)(Xb + (size_t)r * IN_F + k0 + tcol),
                    (lv_t*)(As + r * BK + tcol), 16, 0, 0);
            __builtin_amdgcn_global_load_lds(
                (gv_t*)(Wb + (size_t)r * IN_F + k0 + tcol),
                (lv_t*)(Bs + r * BK + tcol), 16, 0, 0);
        }
        __syncthreads();   // drain vmcnt (compiler inserts waitcnt)

        s16x8 af[4], bf[4];
        #pragma unroll
        for (int i = 0; i < 4; ++i)
            af[i] = *(const s16x8*)&As[(wm + i * 16 + lrow) * BK + kg * 8];
        #pragma unroll
        for (int j = 0; j < 4; ++j)
            bf[j] = *(const s16x8*)&Bs[(wn + j * 16 + lrow) * BK + kg * 8];

        #pragma unroll
        for (int i = 0; i < 4; ++i)
            #pragma unroll
            for (int j = 0; j < 4; ++j)
                acc[i][j] = __builtin_amdgcn_mfma_f32_16x16x32_bf16(
                    af[i], bf[j], acc[i][j], 0, 0, 0);
    }

    // epilogue: C/D map col = lane&15, row = (lane>>4)*4 + reg
    float bv[4];
    #pragma unroll
    for (int j = 0; j < 4; ++j)
        bv[j] = Bias[(size_t)e_found * OUT_F + n0 + wn + j * 16 + lrow];

    #pragma unroll
    for (int i = 0; i < 4; ++i) {
        #pragma unroll
        for (int r = 0; r < 4; ++r) {
            int rr = wm + i * 16 + kg * 4 + r;
            if (rr < rows) {
                float* yrow = Y + (size_t)(row0 + rr) * OUT_F + n0;
                #pragma unroll
                for (int j = 0; j < 4; ++j)
                    yrow[wn + j * 16 + lrow] = acc[i][j][r] + bv[j];
            }
        }
    }
}

// ---- fallback: round-2 kernel (fp32 inputs, in-kernel cvt) ----
#define LDK 40
__global__ __launch_bounds__(256, 2)
void moe_gemm_f32(const float* __restrict__ X,
                  const void* __restrict__ offp,
                  const float* __restrict__ W,
                  const float* __restrict__ Bias,
                  float* __restrict__ Y,
                  int IN_F, int OUT_F, int NEXP, int Ttot) {
    const bool off_i64 = (((const int*)offp)[NEXP] != Ttot);
    int e_found; long long row0; int rows;
    if (!sched_tile(offp, off_i64, NEXP, blockIdx.y, e_found, row0, rows)) return;

    const int n0 = blockIdx.x * BN;
    const int tid = threadIdx.x;
    const int wave = tid >> 6;
    const int lane = tid & 63;
    const int wm = (wave & 1) * 64;
    const int wn = (wave >> 1) * 64;
    const int lrow = lane & 15;
    const int kg = lane >> 4;

    __shared__ __align__(16) short As[BM][LDK];
    __shared__ __align__(16) short Bs[BN][LDK];

    const float* Xb = X + (size_t)row0 * IN_F;
    const float* Wb = W + (size_t)e_found * OUT_F * IN_F + (size_t)n0 * IN_F;

    f32x4 acc[4][4] = {};

    for (int k0 = 0; k0 < IN_F; k0 += BK) {
        __syncthreads();
        #pragma unroll
        for (int p = 0; p < 4; ++p) {
            int idx = p * 256 + tid;
            int r = idx >> 3;
            int kc = (idx & 7) << 2;
            float4 v = make_float4(0.f, 0.f, 0.f, 0.f);
            if (r < rows) v = *(const float4*)(Xb + (size_t)r * IN_F + k0 + kc);
            s16x4 b;
            b.x = f2bf(v.x); b.y = f2bf(v.y); b.z = f2bf(v.z); b.w = f2bf(v.w);
            *(s16x4*)&As[r][kc] = b;
        }
        #pragma unroll
        for (int p = 0; p < 4; ++p) {
            int idx = p * 256 + tid;
            int r = idx >> 3;
            int kc = (idx & 7) << 2;
            float4 v = *(const float4*)(Wb + (size_t)r * IN_F + k0 + kc);
            s16x4 b;
            b.x = f2bf(v.x); b.y = f2bf(v.y); b.z = f2bf(v.z); b.w = f2bf(v.w);
            *(s16x4*)&Bs[r][kc] = b;
        }
        __syncthreads();

        s16x8 af[4], bf[4];
        #pragma unroll
        for (int i = 0; i < 4; ++i)
            af[i] = *(const s16x8*)&As[wm + i * 16 + lrow][kg * 8];
        #pragma unroll
        for (int j = 0; j < 4; ++j)
            bf[j] = *(const s16x8*)&Bs[wn + j * 16 + lrow][kg * 8];

        #pragma unroll
        for (int i = 0; i < 4; ++i)
            #pragma unroll
            for (int j = 0; j < 4; ++j)
                acc[i][j] = __builtin_amdgcn_mfma_f32_16x16x32_bf16(
                    af[i], bf[j], acc[i][j], 0, 0, 0);
    }

    float bv[4];
    #pragma unroll
    for (int j = 0; j < 4; ++j)
        bv[j] = Bias[(size_t)e_found * OUT_F + n0 + wn + j * 16 + lrow];

    #pragma unroll
    for (int i = 0; i < 4; ++i) {
        #pragma unroll
        for (int r = 0; r < 4; ++r) {
            int rr = wm + i * 16 + kg * 4 + r;
            if (rr < rows) {
                float* yrow = Y + (size_t)(row0 + rr) * OUT_F + n0;
                #pragma unroll
                for (int j = 0; j < 4; ++j)
                    yrow[wn + j * 16 + lrow] = acc[i][j][r] + bv[j];
            }
        }
    }
}

extern "C" void kernel_launch(void* const* d_in, const int* in_sizes, int n_in,
                              void* d_out, int out_size, void* d_ws, size_t ws_size,
                              hipStream_t stream) {
    const float* X = (const float*)d_in[0];
    const void* off = d_in[1];
    const float* W = (const float*)d_in[2];
    const float* Bias = (const float*)d_in[3];
    float* Y = (float*)d_out;

    const int NEXP1 = in_sizes[1];
    const int NEXP = NEXP1 - 1;
    const int OUT_F = in_sizes[3] / NEXP;
    const int IN_F = (int)((long long)in_sizes[2] / NEXP / OUT_F);
    const int T = in_sizes[0] / IN_F;

    const int maxRowTiles = T / BM + NEXP;
    dim3 grid(OUT_F / BN, maxRowTiles);

    const long long Xn = (long long)T * IN_F;                    // elements
    const long long Wn = (long long)NEXP * OUT_F * IN_F;
    const size_t need = (size_t)(Xn + Wn) * sizeof(short);

    if (ws_size >= need) {
        short* wsX = (short*)d_ws;
        short* wsW = wsX + Xn;
        {
            int n4 = (int)(Xn / 4);
            cvt_kernel<<<(n4 + 255) / 256, 256, 0, stream>>>(X, wsX, n4);
        }
        {
            int n4 = (int)(Wn / 4);
            cvt_kernel<<<(n4 + 255) / 256, 256, 0, stream>>>(W, wsW, n4);
        }
        moe_gemm_bf16<<<grid, 256, 0, stream>>>(wsX, off, wsW, Bias, Y,
                                                IN_F, OUT_F, NEXP, T);
    } else {
        moe_gemm_f32<<<grid, 256, 0, stream>>>(X, off, W, Bias, Y,
                                               IN_F, OUT_F, NEXP, T);
    }
}